// Round 5
// baseline (1097.865 us; speedup 1.0000x reference)
//
#include <hip/hip_runtime.h>
#include <cstdint>

typedef __bf16 bf16;
typedef __attribute__((ext_vector_type(8))) __bf16 bf16x8;
typedef __attribute__((ext_vector_type(4))) float f32x4;
typedef __attribute__((ext_vector_type(4))) uint32_t u32x4;
typedef __attribute__((ext_vector_type(2))) uint32_t u32x2;

#define MTOT (8*128*128)   // 131072 tokens total
#define MCH  16384         // tokens per chunk (fallback path)

// async global->LDS, 16B per lane. LDS dest must be linear in lane order
// (wave-uniform base + lane*16) — our layouts are exactly tid*16B. [m97]
#define GLOAD16(g, l) __builtin_amdgcn_global_load_lds( \
    (const __attribute__((address_space(1))) unsigned int*)(g), \
    (__attribute__((address_space(3))) unsigned int*)(l), 16, 0, 0)

// ---------------------------------------------------------------------------
// Weight transpose + cast: fp32 (R x C) -> bf16 (C x R), dims % 32 == 0
// ---------------------------------------------------------------------------
__global__ __launch_bounds__(256)
void transpose_cast_kernel(const float* __restrict__ in, bf16* __restrict__ out,
                           int R, int C) {
    __shared__ float tile[32][33];
    const int tx = threadIdx.x & 31, ty = threadIdx.x >> 5;
    const int c0 = blockIdx.x * 32, r0 = blockIdx.y * 32;
#pragma unroll
    for (int r = ty; r < 32; r += 8) tile[r][tx] = in[(size_t)(r0 + r) * C + c0 + tx];
    __syncthreads();
#pragma unroll
    for (int r = ty; r < 32; r += 8) out[(size_t)(c0 + r) * R + r0 + tx] = (bf16)tile[tx][r];
}

// ---------------------------------------------------------------------------
// Row l2-normalize: fp32 in (320/token) -> bf16 out. 1 wave/token, 4/block.
// ---------------------------------------------------------------------------
__global__ __launch_bounds__(256)
void l2norm_kernel(const float* __restrict__ X, bf16* __restrict__ O) {
    const int tid = threadIdx.x, wv = tid >> 6, lane = tid & 63;
    const size_t row = (size_t)blockIdx.x * 4 + wv;
    const float* xr = X + row * 320;
    bf16* orow = O + row * 320;
    float v[5];
    float ss = 0.f;
#pragma unroll
    for (int r = 0; r < 5; ++r) {
        v[r] = xr[r * 64 + lane];
        ss += v[r] * v[r];
    }
#pragma unroll
    for (int off = 32; off; off >>= 1) ss += __shfl_xor(ss, off);
    const float sc = 1.f / fmaxf(sqrtf(ss), 1e-12f);
#pragma unroll
    for (int r = 0; r < 5; ++r) orow[r * 64 + lane] = (bf16)(v[r] * sc);
}

// ---------------------------------------------------------------------------
// Wide pipelined GEMM: out(MxN) = A(MxK) @ WT(NxK)^T [+ epilogue].
// Block tile 64 x 320; 4 waves, wave wv owns cols [wv*80, wv*80+80).
// Ring-3 LDS (72 KB, 2 blocks/CU) with prefetch depth 2 and COUNTED vmcnt:
//   loop t: [barrier: prev reads done] -> STAGE(t+2) -> vmcnt(12/6/0)+barrier
//           -> ds_read(swizzled) -> 20 MFMA.
// vmcnt never drains to 0 in steady state [T4]; each STAGE = 6 gload_lds ops.
// Bank-conflict fix [T2, rule 21]: gload_lds dest linear; global SOURCE
// 16B-chunk pre-swizzled (^ (t>>3)&3); read applies same XOR
// ((qd ^ (r0>>1)&3)<<3) -> half-wave spreads over all 8 bank-quads.
// EPI: 0 = +bias (bf16)   1 = relu (bf16)
//      2 = res + relu(acc+bias)*gamma (fp32)
//      3 = acc + bias + res, row-l2norm, bf16 (out may alias res)
// ---------------------------------------------------------------------------
template <int EPI, typename OutT>
__global__ __launch_bounds__(256)
void gemm_wide_kernel(const bf16* __restrict__ A, const bf16* __restrict__ WT,
                      const float* __restrict__ bias, const bf16* __restrict__ res,
                      const float* __restrict__ gamma, OutT* __restrict__ out,
                      int K, int N) {
    __shared__ bf16 As[3][64 * 32];    // 3 x 4 KB
    __shared__ bf16 Bs[3][320 * 32];   // 3 x 20 KB
    __shared__ float ssp[64][4];       // EPI=3 cross-wave norm partials
    const int tid = threadIdx.x;
    const int wv = tid >> 6, lane = tid & 63;
    const int n0 = blockIdx.x * 320;
    const int m0 = blockIdx.y * 64;
    const int r0 = lane & 15, qd = lane >> 4;

    f32x4 acc[4][5];
#pragma unroll
    for (int i = 0; i < 4; ++i)
#pragma unroll
        for (int j = 0; j < 5; ++j)
#pragma unroll
            for (int r = 0; r < 4; ++r) acc[i][j][r] = 0.f;

    // staging map: thread t -> row t/4; SOURCE 16B chunk pre-swizzled so the
    // linear LDS dest holds the swizzled layout the reads expect.
    const int sr = tid >> 2;
    const int sc = (((tid & 3) ^ ((tid >> 3) & 3)) << 3);
    const bf16* Ag = A  + (size_t)(m0 + sr) * K + sc;
    const bf16* Bg = WT + (size_t)(n0 + sr) * K + sc;

    auto STAGE = [&](int buf, int kkE) {
        GLOAD16(Ag + kkE, &As[buf][tid * 8]);
#pragma unroll
        for (int g = 0; g < 5; ++g)
            GLOAD16(Bg + (size_t)(g * 64) * K + kkE, &Bs[buf][g * 2048 + tid * 8]);
    };

    const int NT = K >> 5;
    STAGE(0, 0);
    if (NT > 1) STAGE(1, 32);

    // read-side swizzle: row-uniform ((row>>1)&3 == (r0>>1)&3 for all frags)
    const int rsw = ((qd ^ ((r0 >> 1) & 3)) << 3);

    int cur = 0;
    for (int t = 0; t < NT; ++t) {
        // prev iteration's reads retired (consumed by MFMAs) in all waves
        asm volatile("s_barrier" ::: "memory");
        if (t + 2 < NT) {
            int nb = cur + 2; if (nb >= 3) nb -= 3;
            STAGE(nb, (t + 2) << 5);
        }
        const int ahead = NT - 1 - t;   // stages allowed to stay in flight
        if (ahead >= 2)      asm volatile("s_waitcnt vmcnt(12)\n\ts_barrier" ::: "memory");
        else if (ahead == 1) asm volatile("s_waitcnt vmcnt(6)\n\ts_barrier"  ::: "memory");
        else                 asm volatile("s_waitcnt vmcnt(0)\n\ts_barrier"  ::: "memory");
        bf16x8 a[4], b[5];
#pragma unroll
        for (int i = 0; i < 4; ++i)
            a[i] = *(const bf16x8*)(&As[cur][(16 * i + r0) * 32 + rsw]);
#pragma unroll
        for (int j = 0; j < 5; ++j)
            b[j] = *(const bf16x8*)(&Bs[cur][(wv * 80 + 16 * j + r0) * 32 + rsw]);
#pragma unroll
        for (int j = 0; j < 5; ++j)
#pragma unroll
            for (int i = 0; i < 4; ++i)
                acc[i][j] = __builtin_amdgcn_mfma_f32_16x16x32_bf16(a[i], b[j], acc[i][j], 0, 0, 0);
        cur = (cur == 2) ? 0 : cur + 1;
    }

    // D layout: lane holds col = lane&15, rows qd*4 + r  [m89/m91-verified]
    if (EPI == 3) {
        // pass 1: y = acc + bias + residual; per-wave partial ||y||^2 per row
#pragma unroll
        for (int i = 0; i < 4; ++i)
#pragma unroll
            for (int r = 0; r < 4; ++r) {
                const int row = 16 * i + qd * 4 + r;     // 0..63
                float ss2 = 0.f;
#pragma unroll
                for (int j = 0; j < 5; ++j) {
                    const int col = wv * 80 + 16 * j + r0;
                    float v = acc[i][j][r] + bias[col] + (float)res[(size_t)(m0 + row) * 320 + col];
                    acc[i][j][r] = v;
                    ss2 += v * v;
                }
                ss2 += __shfl_xor(ss2, 1);
                ss2 += __shfl_xor(ss2, 2);
                ss2 += __shfl_xor(ss2, 4);
                ss2 += __shfl_xor(ss2, 8);
                if (r0 == 0) ssp[row][wv] = ss2;
            }
        __syncthreads();
        // pass 2: combine partials, scale, write
#pragma unroll
        for (int i = 0; i < 4; ++i)
#pragma unroll
            for (int r = 0; r < 4; ++r) {
                const int row = 16 * i + qd * 4 + r;
                const f32x4 sv = *(const f32x4*)ssp[row];
                const float sc2 = 1.f / fmaxf(sqrtf(sv[0] + sv[1] + sv[2] + sv[3]), 1e-12f);
#pragma unroll
                for (int j = 0; j < 5; ++j)
                    out[(size_t)(m0 + row) * 320 + wv * 80 + 16 * j + r0] =
                        (OutT)(acc[i][j][r] * sc2);
            }
    } else {
#pragma unroll
        for (int i = 0; i < 4; ++i) {
            const int rb = m0 + 16 * i + qd * 4;
#pragma unroll
            for (int j = 0; j < 5; ++j) {
                const int col = n0 + wv * 80 + 16 * j + r0;
                const float bv = (EPI != 1) ? bias[col] : 0.f;
                const float gv = (EPI == 2) ? gamma[col] : 0.f;
#pragma unroll
                for (int r = 0; r < 4; ++r) {
                    const size_t row = (size_t)(rb + r);
                    float v = acc[i][j][r];
                    if (EPI == 0)      v += bv;
                    else if (EPI == 1) v = fmaxf(v, 0.f);
                    else               v = (float)res[row * (size_t)N + col] + fmaxf(v + bv, 0.f) * gv;
                    out[row * (size_t)N + col] = (OutT)v;
                }
            }
        }
    }
}

// ---------------------------------------------------------------------------
// MFMA attention. One wave per (image, window, head); no barriers (all LDS
// wave-private). Per-wave LDS region (10 KB):
//   Vt [0,2048)B    : [16][64] bf16, row dh, col m.  swz ^((row&7)<<4)
//   Ka [2048,6144)B : [64][32] bf16, row m, d 0..31 (10..31 zero). swz ^(((row>>1)&3)<<4)
//   Qb [6144,10240)B: [64][32] bf16, row n.          swz same as Ka
//   Pa [2048,10240)B: [64][64] bf16, row n, col m.   swz ^((row&7)<<4)  (aliases Ka,Qb)
//   invs @ +1536    : 64 f32 (inside Vt rows 12..13, which hold no V data;
//                     those Vt rows feed only dh>=10 lanes, never stored)
// Sequence: stage -> S^T = mfma(K,Q) (16 MFMA) -> col-softmax (2 shfl/col)
//  -> pack P into Pa (16 ds_write_b64, layout = PV A-operand directly)
//  -> O = mfma(Pa, Vt) (8 MFMA) -> scale by 1/sum -> store.
// ---------------------------------------------------------------------------
__global__ __launch_bounds__(256)
void attn_kernel(const bf16* __restrict__ QKV, bf16* __restrict__ AO) {
    __shared__ __align__(16) char smem[40960];
    const int tid = threadIdx.x, wv = tid >> 6, lane = tid & 63;
    const int p = blockIdx.x * 4 + wv;       // pair id
    const int img = p >> 13, pi = p & 8191;  // 8192 pairs per 128x128 image
    const int w = pi >> 5, h = pi & 31;      // window 0..255, head 0..31
    const int wh = w >> 4, ww = w & 15;
    const size_t tokbase = (size_t)img * 16384;
    const size_t tok = tokbase + (size_t)(wh * 8 + (lane >> 3)) * 128 + (ww * 8 + (lane & 7));

    char* reg = smem + wv * 10240;
    bf16* Vt  = (bf16*)reg;
    char* KaB = reg + 2048;
    char* QbB = reg + 6144;
    char* PaB = reg + 2048;
    float* invs = (float*)(reg + 1536);

    const uint32_t* qp = (const uint32_t*)(QKV + tok * 960 + h * 30);  // 4B-aligned
    uint32_t rr[15];
#pragma unroll
    for (int d = 0; d < 15; ++d) rr[d] = qp[d];

    // ---- stage Q, K (rows of 64B, swizzled 16B chunks), V (Vt, b16 writes)
    {
        const int swk = ((lane >> 1) & 3) << 4;
        u32x4 qc0 = {rr[0], rr[1], rr[2], rr[3]};
        u32x4 qc1 = {rr[4], 0u, 0u, 0u};
        u32x4 kc0 = {rr[5], rr[6], rr[7], rr[8]};
        u32x4 kc1 = {rr[9], 0u, 0u, 0u};
        u32x4 zc  = {0u, 0u, 0u, 0u};
        char* qr = QbB + lane * 64;
        char* kr = KaB + lane * 64;
        *(u32x4*)(qr + (0 ^ swk))  = qc0;
        *(u32x4*)(qr + (16 ^ swk)) = qc1;
        *(u32x4*)(qr + (32 ^ swk)) = zc;
        *(u32x4*)(qr + (48 ^ swk)) = zc;
        *(u32x4*)(kr + (0 ^ swk))  = kc0;
        *(u32x4*)(kr + (16 ^ swk)) = kc1;
        *(u32x4*)(kr + (32 ^ swk)) = zc;
        *(u32x4*)(kr + (48 ^ swk)) = zc;
#pragma unroll
        for (int e2 = 0; e2 < 5; ++e2) {
            const uint32_t dv = rr[10 + e2];
            const int e0 = 2 * e2, e1 = 2 * e2 + 1;
            *(uint16_t*)((char*)Vt + ((e0 * 128 + lane * 2) ^ ((e0 & 7) << 4))) = (uint16_t)(dv & 0xffffu);
            *(uint16_t*)((char*)Vt + ((e1 * 128 + lane * 2) ^ ((e1 & 7) << 4))) = (uint16_t)(dv >> 16);
        }
    }
    asm volatile("s_waitcnt lgkmcnt(0)" ::: "memory");  // stage visible (wave-private)
    __builtin_amdgcn_sched_barrier(0);                  // rule #18 fence

    const int r0 = lane & 15, qd = lane >> 4;

    // ---- S^T = K @ Q^T  (A = K rows m, B = Q rows n, k = d padded to 32)
    f32x4 s[4][4];
#pragma unroll
    for (int i = 0; i < 4; ++i)
#pragma unroll
        for (int j = 0; j < 4; ++j)
#pragma unroll
            for (int r = 0; r < 4; ++r) s[i][j][r] = 0.f;
    {
        const int fro = (qd * 16) ^ (((r0 >> 1) & 3) << 4);
        bf16x8 ak[4], bq[4];
#pragma unroll
        for (int i = 0; i < 4; ++i) ak[i] = *(const bf16x8*)(KaB + (16 * i + r0) * 64 + fro);
#pragma unroll
        for (int j = 0; j < 4; ++j) bq[j] = *(const bf16x8*)(QbB + (16 * j + r0) * 64 + fro);
#pragma unroll
        for (int j = 0; j < 4; ++j)
#pragma unroll
            for (int i = 0; i < 4; ++i)
                s[i][j] = __builtin_amdgcn_mfma_f32_16x16x32_bf16(ak[i], bq[j], s[i][j], 0, 0, 0);
    }

    // ---- softmax over m (rows of S^T): in-lane 16 + shfl_xor(16,32)
    const float c = 0.31622776601683794f;    // 10^-0.5
#pragma unroll
    for (int j = 0; j < 4; ++j) {
        float mx = s[0][j][0];
#pragma unroll
        for (int i = 0; i < 4; ++i)
#pragma unroll
            for (int r = 0; r < 4; ++r) mx = fmaxf(mx, s[i][j][r]);
        mx = fmaxf(mx, __shfl_xor(mx, 16));
        mx = fmaxf(mx, __shfl_xor(mx, 32));
        const float nb = -c * mx;
        float sum = 0.f;
#pragma unroll
        for (int i = 0; i < 4; ++i)
#pragma unroll
            for (int r = 0; r < 4; ++r) {
                const float pv = __expf(fmaf(s[i][j][r], c, nb));
                s[i][j][r] = pv;
                sum += pv;
            }
        sum += __shfl_xor(sum, 16);
        sum += __shfl_xor(sum, 32);
        if (qd == 0) invs[16 * j + r0] = 1.f / sum;
    }

    // ---- pack P -> Pa[n][m] (bf16), r-quad is m-consecutive -> b64 writes
#pragma unroll
    for (int j = 0; j < 4; ++j) {
        char* prow = PaB + (16 * j + r0) * 128;
        const int sw = (r0 & 7) << 4;
#pragma unroll
        for (int i = 0; i < 4; ++i) {
            const uint32_t b0 = __builtin_bit_cast(uint16_t, (bf16)s[i][j][0]);
            const uint32_t b1 = __builtin_bit_cast(uint16_t, (bf16)s[i][j][1]);
            const uint32_t b2 = __builtin_bit_cast(uint16_t, (bf16)s[i][j][2]);
            const uint32_t b3 = __builtin_bit_cast(uint16_t, (bf16)s[i][j][3]);
            u32x2 pk = {b0 | (b1 << 16), b2 | (b3 << 16)};
            *(u32x2*)(prow + ((32 * i + 8 * qd) ^ sw)) = pk;
        }
    }
    asm volatile("s_waitcnt lgkmcnt(0)" ::: "memory");  // Pa/invs visible
    __builtin_amdgcn_sched_barrier(0);                  // rule #18 fence

    // ---- O = P @ V  (A = Pa rows n, B = Vt rows dh, k = m over 2 steps)
    f32x4 o[4];
#pragma unroll
    for (int i = 0; i < 4; ++i)
#pragma unroll
        for (int r = 0; r < 4; ++r) o[i][r] = 0.f;
    {
        const int swp = (r0 & 7) << 4;
#pragma unroll
        for (int kk = 0; kk < 2; ++kk) {
            const bf16x8 bV = *(const bf16x8*)((char*)Vt + ((r0 * 128 + kk * 64 + qd * 16) ^ swp));
#pragma unroll
            for (int i = 0; i < 4; ++i) {
                const bf16x8 aP = *(const bf16x8*)(PaB + (((16 * i + r0) * 128 + kk * 64 + qd * 16) ^ swp));
                o[i] = __builtin_amdgcn_mfma_f32_16x16x32_bf16(aP, bV, o[i], 0, 0, 0);
            }
        }
    }

    // ---- scale by 1/sum and store (col dh = r0, valid r0 < 10)
#pragma unroll
    for (int i = 0; i < 4; ++i) {
        const f32x4 iv = *(const f32x4*)(invs + 16 * i + qd * 4);
#pragma unroll
        for (int r = 0; r < 4; ++r) {
            const int n = 16 * i + qd * 4 + r;
            const size_t tn = tokbase + (size_t)(wh * 8 + (n >> 3)) * 128 + (ww * 8 + (n & 7));
            if (r0 < 10)
                AO[tn * 320 + h * 10 + r0] = (bf16)(o[i][r] * iv[r]);
        }
    }
}

// ---------------------------------------------------------------------------
extern "C" void kernel_launch(void* const* d_in, const int* in_sizes, int n_in,
                              void* d_out, int out_size, void* d_ws, size_t ws_size,
                              hipStream_t stream) {
    (void)in_sizes; (void)n_in; (void)out_size;
    const float* x      = (const float*)d_in[0];
    const float* qkv_w  = (const float*)d_in[1];
    const float* qkv_b  = (const float*)d_in[2];
    const float* proj_w = (const float*)d_in[3];
    const float* proj_b = (const float*)d_in[4];
    const float* gamma  = (const float*)d_in[5];
    const float* w1     = (const float*)d_in[6];
    const float* w2     = (const float*)d_in[7];
    const float* b2     = (const float*)d_in[8];
    float* out = (float*)d_out;
    char* ws = (char*)d_ws;

    // full-tensor workspace need:
    //   XN  131072x320  bf16 =  83,886,080
    //   REG max(QKV 960, H1 1280) bf16 = 335,544,320  (H1 aliases dead QKV)
    //   AO  131072x320  bf16 =  83,886,080
    //   WTS transposed weights  =   2,457,600
    const size_t NEED_FULL = 83886080ull + 335544320ull + 83886080ull + 2457600ull;

    if (ws_size >= NEED_FULL) {
        // ---------------- full-M path: 10 launches, no tails ----------------
        bf16* XNb   = (bf16*)(ws);
        bf16* QKV_f = (bf16*)(ws + 83886080ull);
        bf16* H1_f  = QKV_f;
        bf16* AO_f  = (bf16*)(ws + 419430400ull);
        bf16* QT    = (bf16*)(ws + 503316480ull);
        bf16* PT    = QT + 960 * 320;
        bf16* W1T   = PT + 320 * 320;
        bf16* W2T   = W1T + 1280 * 320;

        transpose_cast_kernel<<<dim3(30, 10), 256, 0, stream>>>(qkv_w, QT, 320, 960);
        transpose_cast_kernel<<<dim3(10, 10), 256, 0, stream>>>(proj_w, PT, 320, 320);
        transpose_cast_kernel<<<dim3(40, 10), 256, 0, stream>>>(w1, W1T, 320, 1280);
        transpose_cast_kernel<<<dim3(10, 40), 256, 0, stream>>>(w2, W2T, 1280, 320);

        l2norm_kernel<<<MTOT / 4, 256, 0, stream>>>(x, XNb);

        // QKV: (M x 320) @ (320 x 960) + b
        gemm_wide_kernel<0, bf16><<<dim3(3, MTOT / 64), 256, 0, stream>>>(
            XNb, QT, qkv_b, nullptr, nullptr, QKV_f, 320, 960);

        attn_kernel<<<(MTOT / 64 * 32) / 4, 256, 0, stream>>>(QKV_f, AO_f);

        // proj + bias + residual + l2norm (in-place over XNb)
        gemm_wide_kernel<3, bf16><<<dim3(1, MTOT / 64), 256, 0, stream>>>(
            AO_f, PT, proj_b, XNb, nullptr, XNb, 320, 320);

        // MLP1: relu(Z @ w1)
        gemm_wide_kernel<1, bf16><<<dim3(4, MTOT / 64), 256, 0, stream>>>(
            XNb, W1T, nullptr, nullptr, nullptr, H1_f, 320, 1280);

        // MLP2: out = Z + relu(H1 @ w2 + b2) * gamma  (fp32 out, A read once)
        gemm_wide_kernel<2, float><<<dim3(1, MTOT / 64), 256, 0, stream>>>(
            H1_f, W2T, b2, XNb, gamma, out, 1280, 320);
    } else {
        // ---------------- fallback: 8-chunk path (~62.3 MB ws) ----------------
        bf16* XNb   = (bf16*)(ws);
        bf16* QKV_c = (bf16*)(ws + 10485760ull);
        bf16* H1_c  = QKV_c;
        bf16* AO_c  = (bf16*)(ws + 52428800ull);
        bf16* QT    = (bf16*)(ws + 62914560ull);
        bf16* PT    = QT + 960 * 320;
        bf16* W1T   = PT + 320 * 320;
        bf16* W2T   = W1T + 1280 * 320;

        transpose_cast_kernel<<<dim3(30, 10), 256, 0, stream>>>(qkv_w, QT, 320, 960);
        transpose_cast_kernel<<<dim3(10, 10), 256, 0, stream>>>(proj_w, PT, 320, 320);
        transpose_cast_kernel<<<dim3(40, 10), 256, 0, stream>>>(w1, W1T, 320, 1280);
        transpose_cast_kernel<<<dim3(10, 40), 256, 0, stream>>>(w2, W2T, 1280, 320);

        for (int c = 0; c < 8; ++c) {
            const float* x_c = x + (size_t)c * MCH * 320;
            float* out_c = out + (size_t)c * MCH * 320;

            l2norm_kernel<<<MCH / 4, 256, 0, stream>>>(x_c, XNb);

            gemm_wide_kernel<0, bf16><<<dim3(3, MCH / 64), 256, 0, stream>>>(
                XNb, QT, qkv_b, nullptr, nullptr, QKV_c, 320, 960);

            attn_kernel<<<(256 * 32) / 4, 256, 0, stream>>>(QKV_c, AO_c);

            gemm_wide_kernel<3, bf16><<<dim3(1, MCH / 64), 256, 0, stream>>>(
                AO_c, PT, proj_b, XNb, nullptr, XNb, 320, 320);

            gemm_wide_kernel<1, bf16><<<dim3(4, MCH / 64), 256, 0, stream>>>(
                XNb, W1T, nullptr, nullptr, nullptr, H1_c, 320, 1280);

            gemm_wide_kernel<2, float><<<dim3(1, MCH / 64), 256, 0, stream>>>(
                H1_c, W2T, b2, XNb, gamma, out_c, 1280, 320);
        }
    }
}

// Round 6
// 973.700 us; speedup vs baseline: 1.1275x; 1.1275x over previous
//
#include <hip/hip_runtime.h>
#include <cstdint>

typedef __bf16 bf16;
typedef __attribute__((ext_vector_type(8))) __bf16 bf16x8;
typedef __attribute__((ext_vector_type(4))) float f32x4;
typedef __attribute__((ext_vector_type(4))) uint32_t u32x4;
typedef __attribute__((ext_vector_type(2))) uint32_t u32x2;

#define MTOT (8*128*128)   // 131072 tokens total
#define MCH  16384         // tokens per chunk (fallback path)

// async global->LDS, 16B per lane. LDS dest must be linear in lane order
// (wave-uniform base + lane*16) — our layouts are exactly tid*16B. [m97]
#define GLOAD16(g, l) __builtin_amdgcn_global_load_lds( \
    (const __attribute__((address_space(1))) unsigned int*)(g), \
    (__attribute__((address_space(3))) unsigned int*)(l), 16, 0, 0)

// ---------------------------------------------------------------------------
// Weight transpose + cast: fp32 (R x C) -> bf16 (C x R), dims % 32 == 0
// ---------------------------------------------------------------------------
__global__ __launch_bounds__(256)
void transpose_cast_kernel(const float* __restrict__ in, bf16* __restrict__ out,
                           int R, int C) {
    __shared__ float tile[32][33];
    const int tx = threadIdx.x & 31, ty = threadIdx.x >> 5;
    const int c0 = blockIdx.x * 32, r0 = blockIdx.y * 32;
#pragma unroll
    for (int r = ty; r < 32; r += 8) tile[r][tx] = in[(size_t)(r0 + r) * C + c0 + tx];
    __syncthreads();
#pragma unroll
    for (int r = ty; r < 32; r += 8) out[(size_t)(c0 + r) * R + r0 + tx] = (bf16)tile[tx][r];
}

// ---------------------------------------------------------------------------
// Row l2-normalize: fp32 in (320/token) -> bf16 out. 1 wave/token, 4/block.
// ---------------------------------------------------------------------------
__global__ __launch_bounds__(256)
void l2norm_kernel(const float* __restrict__ X, bf16* __restrict__ O) {
    const int tid = threadIdx.x, wv = tid >> 6, lane = tid & 63;
    const size_t row = (size_t)blockIdx.x * 4 + wv;
    const float* xr = X + row * 320;
    bf16* orow = O + row * 320;
    float v[5];
    float ss = 0.f;
#pragma unroll
    for (int r = 0; r < 5; ++r) {
        v[r] = xr[r * 64 + lane];
        ss += v[r] * v[r];
    }
#pragma unroll
    for (int off = 32; off; off >>= 1) ss += __shfl_xor(ss, off);
    const float sc = 1.f / fmaxf(sqrtf(ss), 1e-12f);
#pragma unroll
    for (int r = 0; r < 5; ++r) orow[r * 64 + lane] = (bf16)(v[r] * sc);
}

// ---------------------------------------------------------------------------
// Wide pipelined GEMM: out(MxN) = A(MxK) @ WT(NxK)^T [+ epilogue].
// Block tile 128 x 320; 4 waves, each wave covers ALL 128 rows and owns cols
// [wv*80, wv*80+80): acc[8][5] (160 VGPR), 40 MFMA : 13 ds_read per K-step.
// Latency-pinned loop (r5 analysis): step time ~ memory latency / depth, so
// we maximize work per step (2x the 64-row tile) at ring-2 + counted vmcnt(7).
// Bank-conflict-free via both-sides XOR swizzle (r5: conflicts == 0):
// gload_lds dest linear; global SOURCE 16B-chunk pre-swizzled (^(tid>>3)&3);
// read applies same XOR ((qd ^ (r0>>1)&3)<<3). Row bits 1:2 are r0-derived
// for every fragment row (16i+r0, wv*80+16j+r0, +64 offsets) so the
// involution matches on both sides.
// EPI: 0 = +bias (bf16)   1 = relu (bf16)
//      2 = res + relu(acc+bias)*gamma (fp32)
//      3 = acc + bias + res, row-l2norm, bf16 (out may alias res)
// ---------------------------------------------------------------------------
template <int EPI, typename OutT>
__global__ __launch_bounds__(256, 2)
void gemm_wide_kernel(const bf16* __restrict__ A, const bf16* __restrict__ WT,
                      const float* __restrict__ bias, const bf16* __restrict__ res,
                      const float* __restrict__ gamma, OutT* __restrict__ out,
                      int K, int N) {
    __shared__ bf16 As[2][128 * 32];   // 2 x 8 KB
    __shared__ bf16 Bs[2][320 * 32];   // 2 x 20 KB
    __shared__ float ssp[128][4];      // EPI=3 cross-wave norm partials
    const int tid = threadIdx.x;
    const int wv = tid >> 6, lane = tid & 63;
    const int n0 = blockIdx.x * 320;
    const int m0 = blockIdx.y * 128;
    const int r0 = lane & 15, qd = lane >> 4;

    f32x4 acc[8][5];
#pragma unroll
    for (int i = 0; i < 8; ++i)
#pragma unroll
        for (int j = 0; j < 5; ++j)
#pragma unroll
            for (int r = 0; r < 4; ++r) acc[i][j][r] = 0.f;

    // staging map: thread t -> row t/4; SOURCE 16B chunk pre-swizzled so the
    // linear LDS dest holds the swizzled layout the reads expect.
    const int sr = tid >> 2;
    const int sc = (((tid & 3) ^ ((tid >> 3) & 3)) << 3);
    const bf16* Ag = A  + (size_t)(m0 + sr) * K + sc;
    const bf16* Bg = WT + (size_t)(n0 + sr) * K + sc;

    auto STAGE = [&](int buf, int kkE) {
        GLOAD16(Ag + kkE, &As[buf][tid * 8]);                        // rows 0..63
        GLOAD16(Ag + (size_t)64 * K + kkE, &As[buf][2048 + tid * 8]); // rows 64..127
#pragma unroll
        for (int g = 0; g < 5; ++g)
            GLOAD16(Bg + (size_t)(g * 64) * K + kkE, &Bs[buf][g * 2048 + tid * 8]);
    };

    const int NT = K >> 5;
    STAGE(0, 0);

    // read-side swizzle: row-uniform ((row>>1)&3 == (r0>>1)&3 for all frags)
    const int rsw = ((qd ^ ((r0 >> 1) & 3)) << 3);

    int cur = 0;
    for (int t = 0; t < NT; ++t) {
        // prev iteration's ds_reads retired (consumed by MFMAs) in all waves
        asm volatile("s_barrier" ::: "memory");
        if (t + 1 < NT) STAGE(cur ^ 1, (t + 1) << 5);
        if (t + 1 < NT) asm volatile("s_waitcnt vmcnt(7)\n\ts_barrier" ::: "memory");
        else            asm volatile("s_waitcnt vmcnt(0)\n\ts_barrier" ::: "memory");
        bf16x8 b[5];
#pragma unroll
        for (int j = 0; j < 5; ++j)
            b[j] = *(const bf16x8*)(&Bs[cur][(wv * 80 + 16 * j + r0) * 32 + rsw]);
#pragma unroll
        for (int ih = 0; ih < 2; ++ih) {
            bf16x8 a[4];
#pragma unroll
            for (int ii = 0; ii < 4; ++ii)
                a[ii] = *(const bf16x8*)(&As[cur][(64 * ih + 16 * ii + r0) * 32 + rsw]);
#pragma unroll
            for (int j = 0; j < 5; ++j)
#pragma unroll
                for (int ii = 0; ii < 4; ++ii)
                    acc[4 * ih + ii][j] =
                        __builtin_amdgcn_mfma_f32_16x16x32_bf16(a[ii], b[j], acc[4 * ih + ii][j], 0, 0, 0);
        }
        cur ^= 1;
    }

    // D layout: lane holds col = lane&15, rows qd*4 + r  [m89/m91-verified]
    if (EPI == 3) {
        // pass 1: y = acc + bias + residual; per-wave partial ||y||^2 per row
#pragma unroll
        for (int i = 0; i < 8; ++i)
#pragma unroll
            for (int r = 0; r < 4; ++r) {
                const int row = 16 * i + qd * 4 + r;     // 0..127
                float ss2 = 0.f;
#pragma unroll
                for (int j = 0; j < 5; ++j) {
                    const int col = wv * 80 + 16 * j + r0;
                    float v = acc[i][j][r] + bias[col] + (float)res[(size_t)(m0 + row) * 320 + col];
                    acc[i][j][r] = v;
                    ss2 += v * v;
                }
                ss2 += __shfl_xor(ss2, 1);
                ss2 += __shfl_xor(ss2, 2);
                ss2 += __shfl_xor(ss2, 4);
                ss2 += __shfl_xor(ss2, 8);
                if (r0 == 0) ssp[row][wv] = ss2;
            }
        __syncthreads();
        // pass 2: combine partials, scale, write
#pragma unroll
        for (int i = 0; i < 8; ++i)
#pragma unroll
            for (int r = 0; r < 4; ++r) {
                const int row = 16 * i + qd * 4 + r;
                const f32x4 sv = *(const f32x4*)ssp[row];
                const float sc2 = 1.f / fmaxf(sqrtf(sv[0] + sv[1] + sv[2] + sv[3]), 1e-12f);
#pragma unroll
                for (int j = 0; j < 5; ++j)
                    out[(size_t)(m0 + row) * 320 + wv * 80 + 16 * j + r0] =
                        (OutT)(acc[i][j][r] * sc2);
            }
    } else {
#pragma unroll
        for (int i = 0; i < 8; ++i) {
            const int rb = m0 + 16 * i + qd * 4;
#pragma unroll
            for (int j = 0; j < 5; ++j) {
                const int col = n0 + wv * 80 + 16 * j + r0;
                const float bv = (EPI != 1) ? bias[col] : 0.f;
                const float gv = (EPI == 2) ? gamma[col] : 0.f;
#pragma unroll
                for (int r = 0; r < 4; ++r) {
                    const size_t row = (size_t)(rb + r);
                    float v = acc[i][j][r];
                    if (EPI == 0)      v += bv;
                    else if (EPI == 1) v = fmaxf(v, 0.f);
                    else               v = (float)res[row * (size_t)N + col] + fmaxf(v + bv, 0.f) * gv;
                    out[row * (size_t)N + col] = (OutT)v;
                }
            }
        }
    }
}

// ---------------------------------------------------------------------------
// MFMA attention. One wave per (image, window, head); no barriers (all LDS
// wave-private). Per-wave LDS region (10 KB):
//   Vt [0,2048)B    : [16][64] bf16, row dh, col m.  swz ^((row&7)<<4)
//   Ka [2048,6144)B : [64][32] bf16, row m, d 0..31 (10..31 zero). swz ^(((row>>1)&3)<<4)
//   Qb [6144,10240)B: [64][32] bf16, row n.          swz same as Ka
//   Pa [2048,10240)B: [64][64] bf16, row n, col m.   swz ^((row&7)<<4)  (aliases Ka,Qb)
//   invs @ +1536    : 64 f32 (inside Vt rows 12..13, which hold no V data;
//                     those Vt rows feed only dh>=10 lanes, never stored)
// Sequence: stage -> S^T = mfma(K,Q) (16 MFMA) -> col-softmax (2 shfl/col)
//  -> pack P into Pa (16 ds_write_b64, layout = PV A-operand directly)
//  -> O = mfma(Pa, Vt) (8 MFMA) -> scale by 1/sum -> store.
// ---------------------------------------------------------------------------
__global__ __launch_bounds__(256)
void attn_kernel(const bf16* __restrict__ QKV, bf16* __restrict__ AO) {
    __shared__ __align__(16) char smem[40960];
    const int tid = threadIdx.x, wv = tid >> 6, lane = tid & 63;
    const int p = blockIdx.x * 4 + wv;       // pair id
    const int img = p >> 13, pi = p & 8191;  // 8192 pairs per 128x128 image
    const int w = pi >> 5, h = pi & 31;      // window 0..255, head 0..31
    const int wh = w >> 4, ww = w & 15;
    const size_t tokbase = (size_t)img * 16384;
    const size_t tok = tokbase + (size_t)(wh * 8 + (lane >> 3)) * 128 + (ww * 8 + (lane & 7));

    char* reg = smem + wv * 10240;
    bf16* Vt  = (bf16*)reg;
    char* KaB = reg + 2048;
    char* QbB = reg + 6144;
    char* PaB = reg + 2048;
    float* invs = (float*)(reg + 1536);

    const uint32_t* qp = (const uint32_t*)(QKV + tok * 960 + h * 30);  // 4B-aligned
    uint32_t rr[15];
#pragma unroll
    for (int d = 0; d < 15; ++d) rr[d] = qp[d];

    // ---- stage Q, K (rows of 64B, swizzled 16B chunks), V (Vt, b16 writes)
    {
        const int swk = ((lane >> 1) & 3) << 4;
        u32x4 qc0 = {rr[0], rr[1], rr[2], rr[3]};
        u32x4 qc1 = {rr[4], 0u, 0u, 0u};
        u32x4 kc0 = {rr[5], rr[6], rr[7], rr[8]};
        u32x4 kc1 = {rr[9], 0u, 0u, 0u};
        u32x4 zc  = {0u, 0u, 0u, 0u};
        char* qr = QbB + lane * 64;
        char* kr = KaB + lane * 64;
        *(u32x4*)(qr + (0 ^ swk))  = qc0;
        *(u32x4*)(qr + (16 ^ swk)) = qc1;
        *(u32x4*)(qr + (32 ^ swk)) = zc;
        *(u32x4*)(qr + (48 ^ swk)) = zc;
        *(u32x4*)(kr + (0 ^ swk))  = kc0;
        *(u32x4*)(kr + (16 ^ swk)) = kc1;
        *(u32x4*)(kr + (32 ^ swk)) = zc;
        *(u32x4*)(kr + (48 ^ swk)) = zc;
#pragma unroll
        for (int e2 = 0; e2 < 5; ++e2) {
            const uint32_t dv = rr[10 + e2];
            const int e0 = 2 * e2, e1 = 2 * e2 + 1;
            *(uint16_t*)((char*)Vt + ((e0 * 128 + lane * 2) ^ ((e0 & 7) << 4))) = (uint16_t)(dv & 0xffffu);
            *(uint16_t*)((char*)Vt + ((e1 * 128 + lane * 2) ^ ((e1 & 7) << 4))) = (uint16_t)(dv >> 16);
        }
    }
    asm volatile("s_waitcnt lgkmcnt(0)" ::: "memory");  // stage visible (wave-private)
    __builtin_amdgcn_sched_barrier(0);                  // rule #18 fence

    const int r0 = lane & 15, qd = lane >> 4;

    // ---- S^T = K @ Q^T  (A = K rows m, B = Q rows n, k = d padded to 32)
    f32x4 s[4][4];
#pragma unroll
    for (int i = 0; i < 4; ++i)
#pragma unroll
        for (int j = 0; j < 4; ++j)
#pragma unroll
            for (int r = 0; r < 4; ++r) s[i][j][r] = 0.f;
    {
        const int fro = (qd * 16) ^ (((r0 >> 1) & 3) << 4);
        bf16x8 ak[4], bq[4];
#pragma unroll
        for (int i = 0; i < 4; ++i) ak[i] = *(const bf16x8*)(KaB + (16 * i + r0) * 64 + fro);
#pragma unroll
        for (int j = 0; j < 4; ++j) bq[j] = *(const bf16x8*)(QbB + (16 * j + r0) * 64 + fro);
#pragma unroll
        for (int j = 0; j < 4; ++j)
#pragma unroll
            for (int i = 0; i < 4; ++i)
                s[i][j] = __builtin_amdgcn_mfma_f32_16x16x32_bf16(ak[i], bq[j], s[i][j], 0, 0, 0);
    }

    // ---- softmax over m (rows of S^T): in-lane 16 + shfl_xor(16,32)
    const float c = 0.31622776601683794f;    // 10^-0.5
#pragma unroll
    for (int j = 0; j < 4; ++j) {
        float mx = s[0][j][0];
#pragma unroll
        for (int i = 0; i < 4; ++i)
#pragma unroll
            for (int r = 0; r < 4; ++r) mx = fmaxf(mx, s[i][j][r]);
        mx = fmaxf(mx, __shfl_xor(mx, 16));
        mx = fmaxf(mx, __shfl_xor(mx, 32));
        const float nb = -c * mx;
        float sum = 0.f;
#pragma unroll
        for (int i = 0; i < 4; ++i)
#pragma unroll
            for (int r = 0; r < 4; ++r) {
                const float pv = __expf(fmaf(s[i][j][r], c, nb));
                s[i][j][r] = pv;
                sum += pv;
            }
        sum += __shfl_xor(sum, 16);
        sum += __shfl_xor(sum, 32);
        if (qd == 0) invs[16 * j + r0] = 1.f / sum;
    }

    // ---- pack P -> Pa[n][m] (bf16), r-quad is m-consecutive -> b64 writes
#pragma unroll
    for (int j = 0; j < 4; ++j) {
        char* prow = PaB + (16 * j + r0) * 128;
        const int sw = (r0 & 7) << 4;
#pragma unroll
        for (int i = 0; i < 4; ++i) {
            const uint32_t b0 = __builtin_bit_cast(uint16_t, (bf16)s[i][j][0]);
            const uint32_t b1 = __builtin_bit_cast(uint16_t, (bf16)s[i][j][1]);
            const uint32_t b2 = __builtin_bit_cast(uint16_t, (bf16)s[i][j][2]);
            const uint32_t b3 = __builtin_bit_cast(uint16_t, (bf16)s[i][j][3]);
            u32x2 pk = {b0 | (b1 << 16), b2 | (b3 << 16)};
            *(u32x2*)(prow + ((32 * i + 8 * qd) ^ sw)) = pk;
        }
    }
    asm volatile("s_waitcnt lgkmcnt(0)" ::: "memory");  // Pa/invs visible
    __builtin_amdgcn_sched_barrier(0);                  // rule #18 fence

    // ---- O = P @ V  (A = Pa rows n, B = Vt rows dh, k = m over 2 steps)
    f32x4 o[4];
#pragma unroll
    for (int i = 0; i < 4; ++i)
#pragma unroll
        for (int r = 0; r < 4; ++r) o[i][r] = 0.f;
    {
        const int swp = (r0 & 7) << 4;
#pragma unroll
        for (int kk = 0; kk < 2; ++kk) {
            const bf16x8 bV = *(const bf16x8*)((char*)Vt + ((r0 * 128 + kk * 64 + qd * 16) ^ swp));
#pragma unroll
            for (int i = 0; i < 4; ++i) {
                const bf16x8 aP = *(const bf16x8*)(PaB + (((16 * i + r0) * 128 + kk * 64 + qd * 16) ^ swp));
                o[i] = __builtin_amdgcn_mfma_f32_16x16x32_bf16(aP, bV, o[i], 0, 0, 0);
            }
        }
    }

    // ---- scale by 1/sum and store (col dh = r0, valid r0 < 10)
#pragma unroll
    for (int i = 0; i < 4; ++i) {
        const f32x4 iv = *(const f32x4*)(invs + 16 * i + qd * 4);
#pragma unroll
        for (int r = 0; r < 4; ++r) {
            const int n = 16 * i + qd * 4 + r;
            const size_t tn = tokbase + (size_t)(wh * 8 + (n >> 3)) * 128 + (ww * 8 + (n & 7));
            if (r0 < 10)
                AO[tn * 320 + h * 10 + r0] = (bf16)(o[i][r] * iv[r]);
        }
    }
}

// ---------------------------------------------------------------------------
extern "C" void kernel_launch(void* const* d_in, const int* in_sizes, int n_in,
                              void* d_out, int out_size, void* d_ws, size_t ws_size,
                              hipStream_t stream) {
    (void)in_sizes; (void)n_in; (void)out_size;
    const float* x      = (const float*)d_in[0];
    const float* qkv_w  = (const float*)d_in[1];
    const float* qkv_b  = (const float*)d_in[2];
    const float* proj_w = (const float*)d_in[3];
    const float* proj_b = (const float*)d_in[4];
    const float* gamma  = (const float*)d_in[5];
    const float* w1     = (const float*)d_in[6];
    const float* w2     = (const float*)d_in[7];
    const float* b2     = (const float*)d_in[8];
    float* out = (float*)d_out;
    char* ws = (char*)d_ws;

    // full-tensor workspace need:
    //   XN  131072x320  bf16 =  83,886,080
    //   REG max(QKV 960, H1 1280) bf16 = 335,544,320  (H1 aliases dead QKV)
    //   AO  131072x320  bf16 =  83,886,080
    //   WTS transposed weights  =   2,457,600
    const size_t NEED_FULL = 83886080ull + 335544320ull + 83886080ull + 2457600ull;

    if (ws_size >= NEED_FULL) {
        // ---------------- full-M path: 10 launches, no tails ----------------
        bf16* XNb   = (bf16*)(ws);
        bf16* QKV_f = (bf16*)(ws + 83886080ull);
        bf16* H1_f  = QKV_f;
        bf16* AO_f  = (bf16*)(ws + 419430400ull);
        bf16* QT    = (bf16*)(ws + 503316480ull);
        bf16* PT    = QT + 960 * 320;
        bf16* W1T   = PT + 320 * 320;
        bf16* W2T   = W1T + 1280 * 320;

        transpose_cast_kernel<<<dim3(30, 10), 256, 0, stream>>>(qkv_w, QT, 320, 960);
        transpose_cast_kernel<<<dim3(10, 10), 256, 0, stream>>>(proj_w, PT, 320, 320);
        transpose_cast_kernel<<<dim3(40, 10), 256, 0, stream>>>(w1, W1T, 320, 1280);
        transpose_cast_kernel<<<dim3(10, 40), 256, 0, stream>>>(w2, W2T, 1280, 320);

        l2norm_kernel<<<MTOT / 4, 256, 0, stream>>>(x, XNb);

        // QKV: (M x 320) @ (320 x 960) + b
        gemm_wide_kernel<0, bf16><<<dim3(3, MTOT / 128), 256, 0, stream>>>(
            XNb, QT, qkv_b, nullptr, nullptr, QKV_f, 320, 960);

        attn_kernel<<<(MTOT / 64 * 32) / 4, 256, 0, stream>>>(QKV_f, AO_f);

        // proj + bias + residual + l2norm (in-place over XNb)
        gemm_wide_kernel<3, bf16><<<dim3(1, MTOT / 128), 256, 0, stream>>>(
            AO_f, PT, proj_b, XNb, nullptr, XNb, 320, 320);

        // MLP1: relu(Z @ w1)
        gemm_wide_kernel<1, bf16><<<dim3(4, MTOT / 128), 256, 0, stream>>>(
            XNb, W1T, nullptr, nullptr, nullptr, H1_f, 320, 1280);

        // MLP2: out = Z + relu(H1 @ w2 + b2) * gamma  (fp32 out, A read once)
        gemm_wide_kernel<2, float><<<dim3(1, MTOT / 128), 256, 0, stream>>>(
            H1_f, W2T, b2, XNb, gamma, out, 1280, 320);
    } else {
        // ---------------- fallback: 8-chunk path (~62.3 MB ws) ----------------
        bf16* XNb   = (bf16*)(ws);
        bf16* QKV_c = (bf16*)(ws + 10485760ull);
        bf16* H1_c  = QKV_c;
        bf16* AO_c  = (bf16*)(ws + 52428800ull);
        bf16* QT    = (bf16*)(ws + 62914560ull);
        bf16* PT    = QT + 960 * 320;
        bf16* W1T   = PT + 320 * 320;
        bf16* W2T   = W1T + 1280 * 320;

        transpose_cast_kernel<<<dim3(30, 10), 256, 0, stream>>>(qkv_w, QT, 320, 960);
        transpose_cast_kernel<<<dim3(10, 10), 256, 0, stream>>>(proj_w, PT, 320, 320);
        transpose_cast_kernel<<<dim3(40, 10), 256, 0, stream>>>(w1, W1T, 320, 1280);
        transpose_cast_kernel<<<dim3(10, 40), 256, 0, stream>>>(w2, W2T, 1280, 320);

        for (int c = 0; c < 8; ++c) {
            const float* x_c = x + (size_t)c * MCH * 320;
            float* out_c = out + (size_t)c * MCH * 320;

            l2norm_kernel<<<MCH / 4, 256, 0, stream>>>(x_c, XNb);

            gemm_wide_kernel<0, bf16><<<dim3(3, MCH / 128), 256, 0, stream>>>(
                XNb, QT, qkv_b, nullptr, nullptr, QKV_c, 320, 960);

            attn_kernel<<<(256 * 32) / 4, 256, 0, stream>>>(QKV_c, AO_c);

            gemm_wide_kernel<3, bf16><<<dim3(1, MCH / 128), 256, 0, stream>>>(
                AO_c, PT, proj_b, XNb, nullptr, XNb, 320, 320);

            gemm_wide_kernel<1, bf16><<<dim3(4, MCH / 128), 256, 0, stream>>>(
                XNb, W1T, nullptr, nullptr, nullptr, H1_c, 320, 1280);

            gemm_wide_kernel<2, float><<<dim3(1, MCH / 128), 256, 0, stream>>>(
                H1_c, W2T, b2, XNb, gamma, out_c, 1280, 320);
        }
    }
}